// Round 9
// baseline (202.376 us; speedup 1.0000x reference)
//
#include <hip/hip_runtime.h>
#include <hip/hip_fp16.h>
#include <math.h>

// GCN, aggregate-then-transform, R9: agg+transform fused per layer via LDS
// hand-off (block grid-strides over 16-node groups; agg in registers ->
// 2KB LDS -> same block transforms with register-resident weights).
// CSR via slab bucket sort. eb packed: (src<<8)|(dst&255). u rows fp16,
// stride 32 halves = 64B line.

#define TPB 256
#define BSH 8                 // 256 nodes per bucket
#define BNODES 256
#define MAXBUCK 512
#define CH 8192               // edges per partition block
#define CAPSH 12              // slab capacity 4096 entries/bucket
#define CAP (1 << CAPSH)

// partition edges into per-bucket slabs; bcursor is RELATIVE (memset 0).
__global__ void k_part(const int* __restrict__ src, const int* __restrict__ dst,
                       int* __restrict__ bcursor, int* __restrict__ eb,
                       int E, int nbuck) {
    __shared__ int lh[MAXBUCK];
    __shared__ int lbase[MAXBUCK];
    int t = threadIdx.x;
    int chunk0 = blockIdx.x * CH;
    int end = min(chunk0 + CH, E);
    const int4* dst4 = (const int4*)dst;
    const int4* src4 = (const int4*)src;
    for (int i = t; i < nbuck; i += TPB) lh[i] = 0;
    __syncthreads();
    for (int e4 = chunk0 / 4 + t; e4 * 4 < end; e4 += TPB) {
        int base = e4 * 4;
        int4 d = dst4[e4];
        if (base + 0 < end) atomicAdd(&lh[d.x >> BSH], 1);
        if (base + 1 < end) atomicAdd(&lh[d.y >> BSH], 1);
        if (base + 2 < end) atomicAdd(&lh[d.z >> BSH], 1);
        if (base + 3 < end) atomicAdd(&lh[d.w >> BSH], 1);
    }
    __syncthreads();
    for (int i = t; i < nbuck; i += TPB) {
        int c = lh[i];
        lbase[i] = c ? atomicAdd(&bcursor[i], c) : 0;
        lh[i] = 0;
    }
    __syncthreads();
    for (int e4 = chunk0 / 4 + t; e4 * 4 < end; e4 += TPB) {
        int base = e4 * 4;
        int4 d = dst4[e4];
        int4 s = src4[e4];
        #define PUT(c, sv) if (base + c < end) { \
            int b = (d.sv) >> BSH; \
            int r = lbase[b] + atomicAdd(&lh[b], 1); \
            if (r < CAP) \
                eb[((size_t)b << CAPSH) + r] = ((s.sv) << BSH) | ((d.sv) & (BNODES - 1)); }
        PUT(0, x) PUT(1, y) PUT(2, z) PUT(3, w)
        #undef PUT
    }
}

// per bucket: LDS counting sort within slab -> csr (slab space), row_start,
// cnt, dinv, plus u1h = fp16(x*dinv) rows (stride 32 halves, pad zeroed).
__global__ void k_bucket(const int* __restrict__ eb, const int* __restrict__ bcursor,
                         const float* __restrict__ x,
                         int* __restrict__ csr, int* __restrict__ row_start,
                         int* __restrict__ cnt, float* __restrict__ dinv,
                         __half* __restrict__ u1h, int n) {
    __shared__ int lcnt[BNODES];
    __shared__ int lscan[BNODES];
    __shared__ float ldinv[BNODES];
    int b = blockIdx.x;
    int t = threadIdx.x;
    int node0 = b << BSH;
    int beg = b << CAPSH;
    int end = beg + min(bcursor[b], CAP);
    lcnt[t] = 0;
    __syncthreads();
    for (int i = beg + t; i < end; i += TPB)
        atomicAdd(&lcnt[eb[i] & (BNODES - 1)], 1);
    __syncthreads();
    int v = lcnt[t];
    lscan[t] = v;
    __syncthreads();
    for (int off = 1; off < TPB; off <<= 1) {
        int xx = (t >= off) ? lscan[t - off] : 0;
        __syncthreads();
        lscan[t] += xx;
        __syncthreads();
    }
    int excl = lscan[t] - v;
    int node = node0 + t;
    float dv = rsqrtf(1.0f + (float)v);
    ldinv[t] = dv;
    if (node < n) {
        row_start[node] = beg + excl;
        cnt[node] = v;
        dinv[node] = dv;
    }
    __syncthreads();
    lcnt[t] = excl;
    __syncthreads();
    for (int i = beg + t; i < end; i += TPB) {
        int e = eb[i];
        int p = atomicAdd(&lcnt[e & (BNODES - 1)], 1);
        csr[beg + p] = e >> BSH;
    }
    int nn = min(BNODES, n - node0);
    int tot = nn * 32;
    const float* xb = x + (size_t)node0 * 18;
    __half* ub = u1h + (size_t)node0 * 32;
    for (int i = t; i < tot; i += TPB) {
        int nl = i >> 5, f = i & 31;
        float val = (f < 18) ? xb[nl * 18 + f] * ldinv[nl] : 0.f;
        ub[i] = __float2half_rn(val);
    }
}

// fused layer 1: grid-stride over 16-node groups.
// Phase A (agg): 16 lanes/node, lane owns half2 pair f2; register float2 acc;
//   per edge one broadcast csr read + one coalesced 64B row load. -> LDS.
// Phase B (transform): wave w handles nodes {w,4+w,8+w,12+w}; row from LDS
//   (same-address broadcast), W1 col f in 18 VGPRs; writes u2h fp16 row.
__global__ void k_fused1(const __half2* __restrict__ u1h2, const int* __restrict__ row_start,
                         const int* __restrict__ cnt, const int* __restrict__ csr,
                         const float* __restrict__ dinv, const float* __restrict__ W1,
                         const float* __restrict__ b1, __half* __restrict__ u2h,
                         int n, int ngroups) {
    __shared__ float lagg[16][19];   // 18 used +1 pad
    int t = threadIdx.x;
    int lane = t & 63, wv = t >> 6;
    int f2 = t & 15, nl = t >> 4;
    int f = lane & 31;
    float w1r[18];
#pragma unroll
    for (int k = 0; k < 18; ++k) w1r[k] = W1[k * 32 + f];
    float b1v = b1[f];
    for (int g = blockIdx.x; g < ngroups; g += gridDim.x) {
        int node = g * 16 + nl;
        float2 acc = make_float2(0.f, 0.f);
        if (node < n) {
            acc = __half22float2(u1h2[(size_t)node * 16 + f2]);
            int beg = row_start[node], num = cnt[node];
            int i = 0;
            for (; i + 4 <= num; i += 4) {
                int s0 = csr[beg + i], s1 = csr[beg + i + 1];
                int s2 = csr[beg + i + 2], s3 = csr[beg + i + 3];
                float2 v0 = __half22float2(u1h2[(size_t)s0 * 16 + f2]);
                float2 v1 = __half22float2(u1h2[(size_t)s1 * 16 + f2]);
                float2 v2 = __half22float2(u1h2[(size_t)s2 * 16 + f2]);
                float2 v3 = __half22float2(u1h2[(size_t)s3 * 16 + f2]);
                acc.x += (v0.x + v1.x) + (v2.x + v3.x);
                acc.y += (v0.y + v1.y) + (v2.y + v3.y);
            }
            for (; i < num; ++i) {
                int s = csr[beg + i];
                float2 v = __half22float2(u1h2[(size_t)s * 16 + f2]);
                acc.x += v.x;
                acc.y += v.y;
            }
        }
        if (f2 < 9) {
            lagg[nl][2 * f2] = acc.x;
            lagg[nl][2 * f2 + 1] = acc.y;
        }
        __syncthreads();
#pragma unroll
        for (int rr = 0; rr < 4; ++rr) {
            int nl2 = rr * 4 + wv;
            int node2 = g * 16 + nl2;
            if (node2 < n) {
                float a = 0.f;
#pragma unroll
                for (int k = 0; k < 18; ++k) a = fmaf(lagg[nl2][k], w1r[k], a);
                float di = dinv[node2];
                if (lane < 32)
                    u2h[(size_t)node2 * 32 + f] =
                        __float2half_rn(fmaxf(fmaf(di, a, b1v), 0.f) * di);
            }
        }
        __syncthreads();
    }
}

// fused layer 2 + head: same structure; transform lane owns output o=lane
// (W2 col in 32 VGPRs), FC(64->2) via shfl butterfly + log_softmax.
__global__ void k_fused2(const __half2* __restrict__ u2h2, const int* __restrict__ row_start,
                         const int* __restrict__ cnt, const int* __restrict__ csr,
                         const float* __restrict__ dinv, const float* __restrict__ W2,
                         const float* __restrict__ b2, const float* __restrict__ Wfc,
                         const float* __restrict__ bfc, float* __restrict__ out,
                         int n, int ngroups) {
    __shared__ float lagg[16][33];   // 32 used +1 pad
    int t = threadIdx.x;
    int lane = t & 63, wv = t >> 6;
    int f2 = t & 15, nl = t >> 4;
    float w2r[32];
#pragma unroll
    for (int k = 0; k < 32; ++k) w2r[k] = W2[k * 64 + lane];
    float b2v = b2[lane];
    float wf0 = Wfc[lane * 2 + 0], wf1 = Wfc[lane * 2 + 1];
    float bf0 = bfc[0], bf1 = bfc[1];
    for (int g = blockIdx.x; g < ngroups; g += gridDim.x) {
        int node = g * 16 + nl;
        float2 acc = make_float2(0.f, 0.f);
        if (node < n) {
            acc = __half22float2(u2h2[(size_t)node * 16 + f2]);
            int beg = row_start[node], num = cnt[node];
            int i = 0;
            for (; i + 4 <= num; i += 4) {
                int s0 = csr[beg + i], s1 = csr[beg + i + 1];
                int s2 = csr[beg + i + 2], s3 = csr[beg + i + 3];
                float2 v0 = __half22float2(u2h2[(size_t)s0 * 16 + f2]);
                float2 v1 = __half22float2(u2h2[(size_t)s1 * 16 + f2]);
                float2 v2 = __half22float2(u2h2[(size_t)s2 * 16 + f2]);
                float2 v3 = __half22float2(u2h2[(size_t)s3 * 16 + f2]);
                acc.x += (v0.x + v1.x) + (v2.x + v3.x);
                acc.y += (v0.y + v1.y) + (v2.y + v3.y);
            }
            for (; i < num; ++i) {
                int s = csr[beg + i];
                float2 v = __half22float2(u2h2[(size_t)s * 16 + f2]);
                acc.x += v.x;
                acc.y += v.y;
            }
        }
        lagg[nl][2 * f2] = acc.x;
        lagg[nl][2 * f2 + 1] = acc.y;
        __syncthreads();
#pragma unroll
        for (int rr = 0; rr < 4; ++rr) {
            int nl2 = rr * 4 + wv;
            int node2 = g * 16 + nl2;
            float a0 = 0.f, a1 = 0.f, a2 = 0.f, a3 = 0.f;
#pragma unroll
            for (int k = 0; k < 32; k += 4) {
                a0 = fmaf(lagg[nl2][k],     w2r[k],     a0);
                a1 = fmaf(lagg[nl2][k + 1], w2r[k + 1], a1);
                a2 = fmaf(lagg[nl2][k + 2], w2r[k + 2], a2);
                a3 = fmaf(lagg[nl2][k + 3], w2r[k + 3], a3);
            }
            float a = (a0 + a1) + (a2 + a3);
            float v = (node2 < n) ? fmaxf(fmaf(dinv[node2], a, b2v), 0.f) : 0.f;
            float l0 = v * wf0;
            float l1 = v * wf1;
#pragma unroll
            for (int off = 32; off >= 1; off >>= 1) {
                l0 += __shfl_xor(l0, off, 64);
                l1 += __shfl_xor(l1, off, 64);
            }
            if (lane == 0 && node2 < n) {
                l0 += bf0;
                l1 += bf1;
                float m2 = fmaxf(l0, l1);
                float lse = m2 + logf(expf(l0 - m2) + expf(l1 - m2));
                out[node2 * 2 + 0] = l0 - lse;
                out[node2 * 2 + 1] = l1 - lse;
            }
        }
        __syncthreads();
    }
}

extern "C" void kernel_launch(void* const* d_in, const int* in_sizes, int n_in,
                              void* d_out, int out_size, void* d_ws, size_t ws_size,
                              hipStream_t stream) {
    const float* x   = (const float*)d_in[0];
    const int*   ei  = (const int*)d_in[1];
    const float* W1  = (const float*)d_in[2];
    const float* b1  = (const float*)d_in[3];
    const float* W2  = (const float*)d_in[4];
    const float* b2  = (const float*)d_in[5];
    const float* Wfc = (const float*)d_in[6];
    const float* bfc = (const float*)d_in[7];
    float* out = (float*)d_out;

    const int n = in_sizes[0] / 18;
    const int E = in_sizes[1] / 2;
    const int* src = ei;
    const int* dst = ei + E;
    const int nbuck = (n + BNODES - 1) >> BSH;

    // ws: bcursor[nbuck] | row_start[n] | cnt[n] | dinv[n]
    //  | eb[nbuck*CAP] | csr[nbuck*CAP] | u1h[n*32 h] | u2h[n*32 h]
    char* w = (char*)d_ws;
    int*    bcursor   = (int*)w;     w += (size_t)nbuck * 4;
    int*    row_start = (int*)w;     w += (size_t)n * 4;
    int*    cnt       = (int*)w;     w += (size_t)n * 4;
    float*  dinv      = (float*)w;   w += (size_t)n * 4;
    int*    eb        = (int*)w;     w += (size_t)nbuck * CAP * 4;
    int*    csr       = (int*)w;     w += (size_t)nbuck * CAP * 4;
    w = (char*)(((size_t)w + 63) & ~(size_t)63);
    __half* u1h       = (__half*)w;  w += (size_t)n * 32 * 2;
    w = (char*)(((size_t)w + 63) & ~(size_t)63);
    __half* u2h       = (__half*)w;  w += (size_t)n * 32 * 2;

    // ---- CSR build: slab bucket sort ----
    hipMemsetAsync(bcursor, 0, (size_t)nbuck * 4, stream);
    k_part<<<(E + CH - 1) / CH, TPB, 0, stream>>>(src, dst, bcursor, eb, E, nbuck);
    k_bucket<<<nbuck, TPB, 0, stream>>>(eb, bcursor, x, csr, row_start, cnt, dinv, u1h, n);

    const int ngroups = (n + 15) / 16;
    const int gridL = min(2048, ngroups);

    k_fused1<<<gridL, TPB, 0, stream>>>((const __half2*)u1h, row_start, cnt, csr,
                                        dinv, W1, b1, u2h, n, ngroups);
    k_fused2<<<gridL, TPB, 0, stream>>>((const __half2*)u2h, row_start, cnt, csr,
                                        dinv, W2, b2, Wfc, bfc, out, n, ngroups);
}

// Round 10
// 195.650 us; speedup vs baseline: 1.0344x; 1.0344x over previous
//
#include <hip/hip_runtime.h>
#include <hip/hip_fp16.h>
#include <math.h>

// GCN, aggregate-then-transform (R8 split structure + R10 padded CSR):
// each node's csr segment padded to 4 entries / 16B alignment; pad slots
// point to zero row (node n) -> agg loop = int4 index load + 4 row gathers,
// no tails, no masks. u rows fp16, stride 32 halves = one 64B line.
// eb packed: (src<<8) | (dst & 255).

#define TPB 256
#define BSH 8                 // 256 nodes per bucket
#define BNODES 256
#define MAXBUCK 512
#define CH 8192               // edges per partition block
#define NPW 8                 // nodes per wave in transform kernels
#define CAPSH 13              // slab capacity 8192 entries/bucket
#define CAP (1 << CAPSH)

// partition edges into per-bucket slabs; bcursor RELATIVE (memset 0).
// block 0 also zeroes the dummy row n of u1h/u2h.
__global__ void k_part(const int* __restrict__ src, const int* __restrict__ dst,
                       int* __restrict__ bcursor, int* __restrict__ eb,
                       __half* __restrict__ u1h, __half* __restrict__ u2h,
                       int E, int n, int nbuck) {
    __shared__ int lh[MAXBUCK];
    __shared__ int lbase[MAXBUCK];
    int t = threadIdx.x;
    if (blockIdx.x == 0 && t < 32) {
        u1h[(size_t)n * 32 + t] = __float2half_rn(0.f);
        u2h[(size_t)n * 32 + t] = __float2half_rn(0.f);
    }
    int chunk0 = blockIdx.x * CH;
    int end = min(chunk0 + CH, E);
    const int4* dst4 = (const int4*)dst;
    const int4* src4 = (const int4*)src;
    for (int i = t; i < nbuck; i += TPB) lh[i] = 0;
    __syncthreads();
    for (int e4 = chunk0 / 4 + t; e4 * 4 < end; e4 += TPB) {
        int base = e4 * 4;
        int4 d = dst4[e4];
        if (base + 0 < end) atomicAdd(&lh[d.x >> BSH], 1);
        if (base + 1 < end) atomicAdd(&lh[d.y >> BSH], 1);
        if (base + 2 < end) atomicAdd(&lh[d.z >> BSH], 1);
        if (base + 3 < end) atomicAdd(&lh[d.w >> BSH], 1);
    }
    __syncthreads();
    for (int i = t; i < nbuck; i += TPB) {
        int c = lh[i];
        lbase[i] = c ? atomicAdd(&bcursor[i], c) : 0;
        lh[i] = 0;
    }
    __syncthreads();
    for (int e4 = chunk0 / 4 + t; e4 * 4 < end; e4 += TPB) {
        int base = e4 * 4;
        int4 d = dst4[e4];
        int4 s = src4[e4];
        #define PUT(c, sv) if (base + c < end) { \
            int b = (d.sv) >> BSH; \
            int r = lbase[b] + atomicAdd(&lh[b], 1); \
            if (r < CAP) \
                eb[((size_t)b << CAPSH) + r] = ((s.sv) << BSH) | ((d.sv) & (BNODES - 1)); }
        PUT(0, x) PUT(1, y) PUT(2, z) PUT(3, w)
        #undef PUT
    }
}

// per bucket: LDS counting sort into PADDED csr segments (each node's start
// 4-aligned, pads filled with node id n = zero row). Also row_start, cnt4
// (= padded_count/4), dinv, and u1h = fp16(x*dinv) rows.
__global__ void k_bucket(const int* __restrict__ eb, const int* __restrict__ bcursor,
                         const float* __restrict__ x,
                         int* __restrict__ csr, int* __restrict__ row_start,
                         int* __restrict__ cnt4, float* __restrict__ dinv,
                         __half* __restrict__ u1h, int n) {
    __shared__ int lcnt[BNODES];
    __shared__ int lscan[BNODES];
    __shared__ float ldinv[BNODES];
    int b = blockIdx.x;
    int t = threadIdx.x;
    int node0 = b << BSH;
    int beg = b << CAPSH;
    int end = beg + min(bcursor[b], CAP);
    lcnt[t] = 0;
    __syncthreads();
    for (int i = beg + t; i < end; i += TPB)
        atomicAdd(&lcnt[eb[i] & (BNODES - 1)], 1);
    __syncthreads();
    int v = lcnt[t];
    int pad = (v + 3) & ~3;          // padded count, multiple of 4
    lscan[t] = pad;
    __syncthreads();
    for (int off = 1; off < TPB; off <<= 1) {
        int xx = (t >= off) ? lscan[t - off] : 0;
        __syncthreads();
        lscan[t] += xx;
        __syncthreads();
    }
    int pexcl = lscan[t] - pad;      // exclusive prefix of padded counts
    int node = node0 + t;
    float dv = rsqrtf(1.0f + (float)v);
    ldinv[t] = dv;
    if (node < n) {
        row_start[node] = beg + pexcl;
        cnt4[node] = pad >> 2;
        dinv[node] = dv;
    }
    __syncthreads();
    lcnt[t] = pexcl;                 // placement cursor
    __syncthreads();
    for (int i = beg + t; i < end; i += TPB) {
        int e = eb[i];
        int p = atomicAdd(&lcnt[e & (BNODES - 1)], 1);
        csr[beg + p] = e >> BSH;
    }
    __syncthreads();
    // fill pad slots with n (zero row)
    for (int p = v; p < pad; ++p) csr[beg + pexcl + p] = n;
    // u1h rows for this bucket (stride 32 halves, zero pad features)
    int nn = min(BNODES, n - node0);
    int tot = nn * 32;
    const float* xb = x + (size_t)node0 * 18;
    __half* ub = u1h + (size_t)node0 * 32;
    for (int i = t; i < tot; i += TPB) {
        int nl = i >> 5, f = i & 31;
        float val = (f < 18) ? xb[nl * 18 + f] * ldinv[nl] : 0.f;
        ub[i] = __float2half_rn(val);
    }
}

// agg: 16 lanes/node, lane owns half2 pair f2. Loop: one int4 index load +
// 4 coalesced 64B row gathers per iteration; no tails, no masks.
template <int OS, int NW>
__global__ void k_agg(const __half2* __restrict__ uh2, const int* __restrict__ row_start,
                      const int* __restrict__ cnt4, const int* __restrict__ csr,
                      float* __restrict__ agg, int n) {
    int t = blockIdx.x * blockDim.x + threadIdx.x;
    int node = t >> 4, f2 = t & 15;
    if (node >= n) return;
    int beg = row_start[node];
    int it = cnt4[node];
    float2 acc = __half22float2(uh2[(size_t)node * 16 + f2]);  // self term
    const int4* ip = (const int4*)(csr + beg);                 // 16B aligned
    for (int i = 0; i < it; ++i) {
        int4 s = ip[i];
        float2 v0 = __half22float2(uh2[(size_t)s.x * 16 + f2]);
        float2 v1 = __half22float2(uh2[(size_t)s.y * 16 + f2]);
        float2 v2 = __half22float2(uh2[(size_t)s.z * 16 + f2]);
        float2 v3 = __half22float2(uh2[(size_t)s.w * 16 + f2]);
        acc.x += (v0.x + v1.x) + (v2.x + v3.x);
        acc.y += (v0.y + v1.y) + (v2.y + v3.y);
    }
    if (f2 < NW) *(float2*)(agg + (size_t)node * OS + 2 * f2) = acc;
}

// l1 transform: wave per NPW nodes; row via wave-uniform scalar loads,
// W1 column f in 18 VGPRs. Out: u2h fp16 rows.
__global__ void k_l1(const float* __restrict__ agg1, const float* __restrict__ W1,
                     const float* __restrict__ dinv, const float* __restrict__ b1,
                     __half* __restrict__ u2h, int n) {
    int lane = threadIdx.x & 63;
    int f = lane & 31;
    int wid = __builtin_amdgcn_readfirstlane((int)(threadIdx.x >> 6));
    int wave = blockIdx.x * (TPB / 64) + wid;
    float w1r[18];
#pragma unroll
    for (int k = 0; k < 18; ++k) w1r[k] = W1[k * 32 + f];
    float b1v = b1[f];
    int node0 = wave * NPW;
    for (int r = 0; r < NPW; ++r) {
        int node = node0 + r;
        if (node >= n) return;
        const float* rp = agg1 + (size_t)node * 18;
        float a = 0.f;
#pragma unroll
        for (int k = 0; k < 18; ++k) a = fmaf(rp[k], w1r[k], a);
        float di = dinv[node];
        if (lane < 32)
            u2h[(size_t)node * 32 + f] =
                __float2half_rn(fmaxf(fmaf(di, a, b1v), 0.f) * di);
    }
}

// l2 transform + head: wave per NPW nodes; row scalar, W2 col (lane) in 32
// VGPRs; FC(64->2) butterfly + log_softmax.
__global__ void k_l2_out(const float* __restrict__ agg2, const float* __restrict__ W2,
                         const float* __restrict__ dinv, const float* __restrict__ b2,
                         const float* __restrict__ Wfc, const float* __restrict__ bfc,
                         float* __restrict__ out, int n) {
    int lane = threadIdx.x & 63;
    int wid = __builtin_amdgcn_readfirstlane((int)(threadIdx.x >> 6));
    int wave = blockIdx.x * (TPB / 64) + wid;
    float w2r[32];
#pragma unroll
    for (int k = 0; k < 32; ++k) w2r[k] = W2[k * 64 + lane];
    float b2v = b2[lane];
    float wf0 = Wfc[lane * 2 + 0], wf1 = Wfc[lane * 2 + 1];
    float bf0 = bfc[0], bf1 = bfc[1];
    int node0 = wave * NPW;
    for (int r = 0; r < NPW; ++r) {
        int node = node0 + r;
        if (node >= n) return;
        const float* rp = agg2 + (size_t)node * 32;
        float a0 = 0.f, a1 = 0.f, a2 = 0.f, a3 = 0.f;
#pragma unroll
        for (int k = 0; k < 32; k += 4) {
            a0 = fmaf(rp[k],     w2r[k],     a0);
            a1 = fmaf(rp[k + 1], w2r[k + 1], a1);
            a2 = fmaf(rp[k + 2], w2r[k + 2], a2);
            a3 = fmaf(rp[k + 3], w2r[k + 3], a3);
        }
        float a = (a0 + a1) + (a2 + a3);
        float v = fmaxf(fmaf(dinv[node], a, b2v), 0.f);
        float l0 = v * wf0;
        float l1 = v * wf1;
#pragma unroll
        for (int off = 32; off >= 1; off >>= 1) {
            l0 += __shfl_xor(l0, off, 64);
            l1 += __shfl_xor(l1, off, 64);
        }
        if (lane == 0) {
            l0 += bf0;
            l1 += bf1;
            float m2 = fmaxf(l0, l1);
            float lse = m2 + logf(expf(l0 - m2) + expf(l1 - m2));
            out[node * 2 + 0] = l0 - lse;
            out[node * 2 + 1] = l1 - lse;
        }
    }
}

extern "C" void kernel_launch(void* const* d_in, const int* in_sizes, int n_in,
                              void* d_out, int out_size, void* d_ws, size_t ws_size,
                              hipStream_t stream) {
    const float* x   = (const float*)d_in[0];
    const int*   ei  = (const int*)d_in[1];
    const float* W1  = (const float*)d_in[2];
    const float* b1  = (const float*)d_in[3];
    const float* W2  = (const float*)d_in[4];
    const float* b2  = (const float*)d_in[5];
    const float* Wfc = (const float*)d_in[6];
    const float* bfc = (const float*)d_in[7];
    float* out = (float*)d_out;

    const int n = in_sizes[0] / 18;
    const int E = in_sizes[1] / 2;
    const int* src = ei;
    const int* dst = ei + E;
    const int nbuck = (n + BNODES - 1) >> BSH;

    // ws: bcursor[nbuck] | row_start[n] | cnt4[n] | dinv[n]
    //  | eb[nbuck*CAP] | csr[nbuck*CAP] | agg1[n*18 f32] | agg2[n*32 f32]
    //  | u1h[(n+1)*32 h] | u2h[(n+1)*32 h]
    char* w = (char*)d_ws;
    int*    bcursor   = (int*)w;     w += (size_t)nbuck * 4;
    int*    row_start = (int*)w;     w += (size_t)n * 4;
    int*    cnt4      = (int*)w;     w += (size_t)n * 4;
    float*  dinv      = (float*)w;   w += (size_t)n * 4;
    int*    eb        = (int*)w;     w += (size_t)nbuck * CAP * 4;
    int*    csr       = (int*)w;     w += (size_t)nbuck * CAP * 4;
    float*  agg1      = (float*)w;   w += (size_t)n * 18 * 4;
    float*  agg2      = (float*)w;   w += (size_t)n * 32 * 4;
    w = (char*)(((size_t)w + 63) & ~(size_t)63);
    __half* u1h       = (__half*)w;  w += (size_t)(n + 1) * 32 * 2;
    w = (char*)(((size_t)w + 63) & ~(size_t)63);
    __half* u2h       = (__half*)w;  w += (size_t)(n + 1) * 32 * 2;

    auto blocks = [](long long work) { return (int)((work + TPB - 1) / TPB); };

    // ---- CSR build: slab bucket sort with padded segments ----
    hipMemsetAsync(bcursor, 0, (size_t)nbuck * 4, stream);
    k_part<<<(E + CH - 1) / CH, TPB, 0, stream>>>(src, dst, bcursor, eb, u1h, u2h, E, n, nbuck);
    k_bucket<<<nbuck, TPB, 0, stream>>>(eb, bcursor, x, csr, row_start, cnt4, dinv, u1h, n);

    const int blocksA = blocks((long long)n * 16);
    const int wavesT = (n + NPW - 1) / NPW;
    const int blocksT = (wavesT + (TPB / 64) - 1) / (TPB / 64);

    // ---- layer 1 ----
    k_agg<18, 9><<<blocksA, TPB, 0, stream>>>((const __half2*)u1h, row_start, cnt4, csr, agg1, n);
    k_l1<<<blocksT, TPB, 0, stream>>>(agg1, W1, dinv, b1, u2h, n);

    // ---- layer 2 + head ----
    k_agg<32, 16><<<blocksA, TPB, 0, stream>>>((const __half2*)u2h, row_start, cnt4, csr, agg2, n);
    k_l2_out<<<blocksT, TPB, 0, stream>>>(agg2, W2, dinv, b2, Wfc, bfc, out, n);
}

// Round 11
// 180.473 us; speedup vs baseline: 1.1214x; 1.0841x over previous
//
#include <hip/hip_runtime.h>
#include <hip/hip_fp16.h>
#include <math.h>

// GCN, R11: split-phase kernels but transform fused into agg via intra-wave
// LDS hand-off (no barriers). Agg: 8 lanes/node (uint2 = 4 halves/lane),
// 8 nodes/wave, padded CSR (int4 idx blocks, pads -> zero row n).
// u rows fp16, stride 32 halves = one 64B line. eb packed (src<<8)|(dst&255).

#define TPB 256
#define BSH 8                 // 256 nodes per bucket
#define BNODES 256
#define MAXBUCK 512
#define CH 8192               // edges per partition block
#define CAPSH 13              // slab capacity 8192 entries/bucket
#define CAP (1 << CAPSH)

// partition edges into per-bucket slabs; bcursor RELATIVE (memset 0).
// block 0 also zeroes the dummy row n of u1h/u2h.
__global__ void k_part(const int* __restrict__ src, const int* __restrict__ dst,
                       int* __restrict__ bcursor, int* __restrict__ eb,
                       __half* __restrict__ u1h, __half* __restrict__ u2h,
                       int E, int n, int nbuck) {
    __shared__ int lh[MAXBUCK];
    __shared__ int lbase[MAXBUCK];
    int t = threadIdx.x;
    if (blockIdx.x == 0 && t < 32) {
        u1h[(size_t)n * 32 + t] = __float2half_rn(0.f);
        u2h[(size_t)n * 32 + t] = __float2half_rn(0.f);
    }
    int chunk0 = blockIdx.x * CH;
    int end = min(chunk0 + CH, E);
    const int4* dst4 = (const int4*)dst;
    const int4* src4 = (const int4*)src;
    for (int i = t; i < nbuck; i += TPB) lh[i] = 0;
    __syncthreads();
    for (int e4 = chunk0 / 4 + t; e4 * 4 < end; e4 += TPB) {
        int base = e4 * 4;
        int4 d = dst4[e4];
        if (base + 0 < end) atomicAdd(&lh[d.x >> BSH], 1);
        if (base + 1 < end) atomicAdd(&lh[d.y >> BSH], 1);
        if (base + 2 < end) atomicAdd(&lh[d.z >> BSH], 1);
        if (base + 3 < end) atomicAdd(&lh[d.w >> BSH], 1);
    }
    __syncthreads();
    for (int i = t; i < nbuck; i += TPB) {
        int c = lh[i];
        lbase[i] = c ? atomicAdd(&bcursor[i], c) : 0;
        lh[i] = 0;
    }
    __syncthreads();
    for (int e4 = chunk0 / 4 + t; e4 * 4 < end; e4 += TPB) {
        int base = e4 * 4;
        int4 d = dst4[e4];
        int4 s = src4[e4];
        #define PUT(c, sv) if (base + c < end) { \
            int b = (d.sv) >> BSH; \
            int r = lbase[b] + atomicAdd(&lh[b], 1); \
            if (r < CAP) \
                eb[((size_t)b << CAPSH) + r] = ((s.sv) << BSH) | ((d.sv) & (BNODES - 1)); }
        PUT(0, x) PUT(1, y) PUT(2, z) PUT(3, w)
        #undef PUT
    }
}

// per bucket: LDS counting sort into PADDED csr segments (4-aligned starts,
// pads = node id n -> zero row). Outputs row_start, cnt4, dinv, u1h rows.
__global__ void k_bucket(const int* __restrict__ eb, const int* __restrict__ bcursor,
                         const float* __restrict__ x,
                         int* __restrict__ csr, int* __restrict__ row_start,
                         int* __restrict__ cnt4, float* __restrict__ dinv,
                         __half* __restrict__ u1h, int n) {
    __shared__ int lcnt[BNODES];
    __shared__ int lscan[BNODES];
    __shared__ float ldinv[BNODES];
    int b = blockIdx.x;
    int t = threadIdx.x;
    int node0 = b << BSH;
    int beg = b << CAPSH;
    int end = beg + min(bcursor[b], CAP);
    lcnt[t] = 0;
    __syncthreads();
    for (int i = beg + t; i < end; i += TPB)
        atomicAdd(&lcnt[eb[i] & (BNODES - 1)], 1);
    __syncthreads();
    int v = lcnt[t];
    int pad = (v + 3) & ~3;
    lscan[t] = pad;
    __syncthreads();
    for (int off = 1; off < TPB; off <<= 1) {
        int xx = (t >= off) ? lscan[t - off] : 0;
        __syncthreads();
        lscan[t] += xx;
        __syncthreads();
    }
    int pexcl = lscan[t] - pad;
    int node = node0 + t;
    float dv = rsqrtf(1.0f + (float)v);
    ldinv[t] = dv;
    if (node < n) {
        row_start[node] = beg + pexcl;
        cnt4[node] = pad >> 2;
        dinv[node] = dv;
    }
    __syncthreads();
    lcnt[t] = pexcl;
    __syncthreads();
    for (int i = beg + t; i < end; i += TPB) {
        int e = eb[i];
        int p = atomicAdd(&lcnt[e & (BNODES - 1)], 1);
        csr[beg + p] = e >> BSH;
    }
    __syncthreads();
    for (int p = v; p < pad; ++p) csr[beg + pexcl + p] = n;
    int nn = min(BNODES, n - node0);
    int tot = nn * 32;
    const float* xb = x + (size_t)node0 * 18;
    __half* ub = u1h + (size_t)node0 * 32;
    for (int i = t; i < tot; i += TPB) {
        int nl = i >> 5, f = i & 31;
        float val = (f < 18) ? xb[nl * 18 + f] * ldinv[nl] : 0.f;
        ub[i] = __float2half_rn(val);
    }
}

// fused layer1: agg (8 lanes/node, uint2 gathers) -> intra-wave LDS ->
// transform (half-wave per node, W1 col f in 18 VGPRs) -> u2h fp16 rows.
__global__ void k_fused1(const uint2* __restrict__ u1q, const int* __restrict__ row_start,
                         const int* __restrict__ cnt4, const int* __restrict__ csr,
                         const float* __restrict__ dinv, const float* __restrict__ W1,
                         const float* __restrict__ b1, __half* __restrict__ u2h,
                         int n) {
    __shared__ float lagg[4][8][33];
    int t = threadIdx.x;
    int lane = t & 63, wv = t >> 6;
    int q = lane & 7, grp = lane >> 3;
    int f = lane & 31, h = lane >> 5;
    float w1r[18];
#pragma unroll
    for (int k = 0; k < 18; ++k) w1r[k] = W1[k * 32 + f];
    float b1v = b1[f];
    int node0 = (blockIdx.x * 4 + wv) * 8;
    int node = node0 + grp;
    float a0 = 0.f, a1 = 0.f, a2 = 0.f, a3 = 0.f;
    if (node < n) {
        uint2 sv = u1q[(size_t)node * 8 + q];
        __half2* sh = (__half2*)&sv;
        float2 s01 = __half22float2(sh[0]), s23 = __half22float2(sh[1]);
        a0 = s01.x; a1 = s01.y; a2 = s23.x; a3 = s23.y;
        int beg = row_start[node];
        int it = cnt4[node];
        const int4* ip = (const int4*)(csr + beg);
        for (int i = 0; i < it; ++i) {
            int4 s = ip[i];
            uint2 v0 = u1q[(size_t)s.x * 8 + q];
            uint2 v1 = u1q[(size_t)s.y * 8 + q];
            uint2 v2 = u1q[(size_t)s.z * 8 + q];
            uint2 v3 = u1q[(size_t)s.w * 8 + q];
            __half2* p0 = (__half2*)&v0; __half2* p1 = (__half2*)&v1;
            __half2* p2 = (__half2*)&v2; __half2* p3 = (__half2*)&v3;
            float2 f00 = __half22float2(p0[0]), f01 = __half22float2(p0[1]);
            float2 f10 = __half22float2(p1[0]), f11 = __half22float2(p1[1]);
            float2 f20 = __half22float2(p2[0]), f21 = __half22float2(p2[1]);
            float2 f30 = __half22float2(p3[0]), f31 = __half22float2(p3[1]);
            a0 += (f00.x + f10.x) + (f20.x + f30.x);
            a1 += (f00.y + f10.y) + (f20.y + f30.y);
            a2 += (f01.x + f11.x) + (f21.x + f31.x);
            a3 += (f01.y + f11.y) + (f21.y + f31.y);
        }
    }
    // intra-wave hand-off (same wave produces and consumes; DS in-order)
    lagg[wv][grp][4 * q + 0] = a0;
    lagg[wv][grp][4 * q + 1] = a1;
    lagg[wv][grp][4 * q + 2] = a2;
    lagg[wv][grp][4 * q + 3] = a3;
    // transform: half-wave h handles nodes node0 + 2r + h
#pragma unroll
    for (int r = 0; r < 4; ++r) {
        int nl = 2 * r + h;
        int nodeT = node0 + nl;
        if (nodeT < n) {
            const float* rp = lagg[wv][nl];
            float a = 0.f;
#pragma unroll
            for (int k = 0; k < 18; ++k) a = fmaf(rp[k], w1r[k], a);
            float di = dinv[nodeT];
            u2h[(size_t)nodeT * 32 + f] =
                __float2half_rn(fmaxf(fmaf(di, a, b1v), 0.f) * di);
        }
    }
}

// fused layer2 + head: agg (8 lanes/node) -> intra-wave LDS -> transform
// (lane = output o, W2 col in 32 VGPRs) -> FC(64->2) butterfly -> lsm.
__global__ void k_fused2(const uint2* __restrict__ u2q, const int* __restrict__ row_start,
                         const int* __restrict__ cnt4, const int* __restrict__ csr,
                         const float* __restrict__ dinv, const float* __restrict__ W2,
                         const float* __restrict__ b2, const float* __restrict__ Wfc,
                         const float* __restrict__ bfc, float* __restrict__ out,
                         int n) {
    __shared__ float lagg[4][8][33];
    int t = threadIdx.x;
    int lane = t & 63, wv = t >> 6;
    int q = lane & 7, grp = lane >> 3;
    float w2r[32];
#pragma unroll
    for (int k = 0; k < 32; ++k) w2r[k] = W2[k * 64 + lane];
    float b2v = b2[lane];
    float wf0 = Wfc[lane * 2 + 0], wf1 = Wfc[lane * 2 + 1];
    float bf0 = bfc[0], bf1 = bfc[1];
    int node0 = (blockIdx.x * 4 + wv) * 8;
    int node = node0 + grp;
    float a0 = 0.f, a1 = 0.f, a2 = 0.f, a3 = 0.f;
    if (node < n) {
        uint2 sv = u2q[(size_t)node * 8 + q];
        __half2* sh = (__half2*)&sv;
        float2 s01 = __half22float2(sh[0]), s23 = __half22float2(sh[1]);
        a0 = s01.x; a1 = s01.y; a2 = s23.x; a3 = s23.y;
        int beg = row_start[node];
        int it = cnt4[node];
        const int4* ip = (const int4*)(csr + beg);
        for (int i = 0; i < it; ++i) {
            int4 s = ip[i];
            uint2 v0 = u2q[(size_t)s.x * 8 + q];
            uint2 v1 = u2q[(size_t)s.y * 8 + q];
            uint2 v2 = u2q[(size_t)s.z * 8 + q];
            uint2 v3 = u2q[(size_t)s.w * 8 + q];
            __half2* p0 = (__half2*)&v0; __half2* p1 = (__half2*)&v1;
            __half2* p2 = (__half2*)&v2; __half2* p3 = (__half2*)&v3;
            float2 f00 = __half22float2(p0[0]), f01 = __half22float2(p0[1]);
            float2 f10 = __half22float2(p1[0]), f11 = __half22float2(p1[1]);
            float2 f20 = __half22float2(p2[0]), f21 = __half22float2(p2[1]);
            float2 f30 = __half22float2(p3[0]), f31 = __half22float2(p3[1]);
            a0 += (f00.x + f10.x) + (f20.x + f30.x);
            a1 += (f00.y + f10.y) + (f20.y + f30.y);
            a2 += (f01.x + f11.x) + (f21.x + f31.x);
            a3 += (f01.y + f11.y) + (f21.y + f31.y);
        }
    }
    lagg[wv][grp][4 * q + 0] = a0;
    lagg[wv][grp][4 * q + 1] = a1;
    lagg[wv][grp][4 * q + 2] = a2;
    lagg[wv][grp][4 * q + 3] = a3;
#pragma unroll
    for (int r = 0; r < 8; ++r) {
        int nodeT = node0 + r;
        const float* rp = lagg[wv][r];
        float c0 = 0.f, c1 = 0.f, c2 = 0.f, c3 = 0.f;
#pragma unroll
        for (int k = 0; k < 32; k += 4) {
            c0 = fmaf(rp[k],     w2r[k],     c0);
            c1 = fmaf(rp[k + 1], w2r[k + 1], c1);
            c2 = fmaf(rp[k + 2], w2r[k + 2], c2);
            c3 = fmaf(rp[k + 3], w2r[k + 3], c3);
        }
        float a = (c0 + c1) + (c2 + c3);
        float v = (nodeT < n) ? fmaxf(fmaf(dinv[nodeT], a, b2v), 0.f) : 0.f;
        float l0 = v * wf0;
        float l1 = v * wf1;
#pragma unroll
        for (int off = 32; off >= 1; off >>= 1) {
            l0 += __shfl_xor(l0, off, 64);
            l1 += __shfl_xor(l1, off, 64);
        }
        if (lane == 0 && nodeT < n) {
            l0 += bf0;
            l1 += bf1;
            float m2 = fmaxf(l0, l1);
            float lse = m2 + logf(expf(l0 - m2) + expf(l1 - m2));
            out[nodeT * 2 + 0] = l0 - lse;
            out[nodeT * 2 + 1] = l1 - lse;
        }
    }
}

extern "C" void kernel_launch(void* const* d_in, const int* in_sizes, int n_in,
                              void* d_out, int out_size, void* d_ws, size_t ws_size,
                              hipStream_t stream) {
    const float* x   = (const float*)d_in[0];
    const int*   ei  = (const int*)d_in[1];
    const float* W1  = (const float*)d_in[2];
    const float* b1  = (const float*)d_in[3];
    const float* W2  = (const float*)d_in[4];
    const float* b2  = (const float*)d_in[5];
    const float* Wfc = (const float*)d_in[6];
    const float* bfc = (const float*)d_in[7];
    float* out = (float*)d_out;

    const int n = in_sizes[0] / 18;
    const int E = in_sizes[1] / 2;
    const int* src = ei;
    const int* dst = ei + E;
    const int nbuck = (n + BNODES - 1) >> BSH;

    // ws: bcursor[nbuck] | row_start[n] | cnt4[n] | dinv[n]
    //  | eb[nbuck*CAP] | csr[nbuck*CAP] | u1h[(n+1)*32 h] | u2h[(n+1)*32 h]
    char* w = (char*)d_ws;
    int*    bcursor   = (int*)w;     w += (size_t)nbuck * 4;
    int*    row_start = (int*)w;     w += (size_t)n * 4;
    int*    cnt4      = (int*)w;     w += (size_t)n * 4;
    float*  dinv      = (float*)w;   w += (size_t)n * 4;
    int*    eb        = (int*)w;     w += (size_t)nbuck * CAP * 4;
    int*    csr       = (int*)w;     w += (size_t)nbuck * CAP * 4;
    w = (char*)(((size_t)w + 63) & ~(size_t)63);
    __half* u1h       = (__half*)w;  w += (size_t)(n + 1) * 32 * 2;
    w = (char*)(((size_t)w + 63) & ~(size_t)63);
    __half* u2h       = (__half*)w;  w += (size_t)(n + 1) * 32 * 2;

    // ---- CSR build: slab bucket sort with padded segments ----
    hipMemsetAsync(bcursor, 0, (size_t)nbuck * 4, stream);
    k_part<<<(E + CH - 1) / CH, TPB, 0, stream>>>(src, dst, bcursor, eb, u1h, u2h, E, n, nbuck);
    k_bucket<<<nbuck, TPB, 0, stream>>>(eb, bcursor, x, csr, row_start, cnt4, dinv, u1h, n);

    const int waves = (n + 7) / 8;
    const int blocksF = (waves + 3) / 4;

    k_fused1<<<blocksF, TPB, 0, stream>>>((const uint2*)u1h, row_start, cnt4, csr,
                                          dinv, W1, b1, u2h, n);
    k_fused2<<<blocksF, TPB, 0, stream>>>((const uint2*)u2h, row_start, cnt4, csr,
                                          dinv, W2, b2, Wfc, bfc, out, n);
}